// Round 3
// baseline (1642.490 us; speedup 1.0000x reference)
//
#include <hip/hip_runtime.h>
#include <math.h>

// 2-layer GAT (PyG GATConv), N=50000, E=1.6M, IN=256.
// Round 3:
//  - bucket sort by dst (64 nodes/bucket) with deterministic placement
//    (per-block hist -> scan of [bucket][chunk] matrix -> LDS-rank scatter),
//    zero global atomics, coalesced-run writes
//  - aggregation: one block per bucket, LDS accumulators (16KB), fused
//    self-loop + softmax-normalize + bias + activation
//  - node_transform: register-blocked 64x64-tile GEMM (4x4 per thread),
//    attention logits fused in epilogue

#define LEAK 0.2f
#define EPSV 1e-16f
#define CHUNK 16384          // edges per sort block
#define BSH 6                // bucket shift: 64 nodes per bucket
#define MAXB 1024            // >= NBUCK (782)

// ---------------- tiled GEMM + attention epilogue ----------------
// grid: ceil(n/64) blocks, 256 threads. Computes xl = x@W [n,64],
// asrc[n,H], adst[n,H].
template<int K, int H, int CH>
__global__ __launch_bounds__(256)
void node_transform(const float* __restrict__ x, const float* __restrict__ W,
                    const float* __restrict__ a_s, const float* __restrict__ a_d,
                    float* __restrict__ xl, float* __restrict__ asrc,
                    float* __restrict__ adst, int n)
{
    __shared__ float xs[64][68];   // nodes x k-chunk (padded); reused as out tile
    __shared__ float ws[64][64];   // k x cols
    int tid = threadIdx.x;
    int tx = tid & 15;             // col group: cols 4*tx..+3
    int ty = tid >> 4;             // node group: nodes 4*ty..+3
    int nbase = blockIdx.x * 64;

    float acc[4][4] = {};
    for (int k0 = 0; k0 < K; k0 += 64) {
        // stage x tile: rows r = ty, ty+16, ...; 16 threads per row load 64 floats
        #pragma unroll
        for (int r = ty; r < 64; r += 16) {
            int node = nbase + r;
            float4 v = make_float4(0.f, 0.f, 0.f, 0.f);
            if (node < n)
                v = *reinterpret_cast<const float4*>(x + (size_t)node * K + k0 + 4 * tx);
            xs[r][4 * tx + 0] = v.x; xs[r][4 * tx + 1] = v.y;
            xs[r][4 * tx + 2] = v.z; xs[r][4 * tx + 3] = v.w;
        }
        // stage W tile
        #pragma unroll
        for (int r = ty; r < 64; r += 16) {
            float4 w = *reinterpret_cast<const float4*>(W + (size_t)(k0 + r) * 64 + 4 * tx);
            ws[r][4 * tx + 0] = w.x; ws[r][4 * tx + 1] = w.y;
            ws[r][4 * tx + 2] = w.z; ws[r][4 * tx + 3] = w.w;
        }
        __syncthreads();
        #pragma unroll 8
        for (int k = 0; k < 64; ++k) {
            float a0 = xs[4 * ty + 0][k], a1 = xs[4 * ty + 1][k];
            float a2 = xs[4 * ty + 2][k], a3 = xs[4 * ty + 3][k];
            float b0 = ws[k][4 * tx + 0], b1 = ws[k][4 * tx + 1];
            float b2 = ws[k][4 * tx + 2], b3 = ws[k][4 * tx + 3];
            acc[0][0] = fmaf(a0, b0, acc[0][0]); acc[0][1] = fmaf(a0, b1, acc[0][1]);
            acc[0][2] = fmaf(a0, b2, acc[0][2]); acc[0][3] = fmaf(a0, b3, acc[0][3]);
            acc[1][0] = fmaf(a1, b0, acc[1][0]); acc[1][1] = fmaf(a1, b1, acc[1][1]);
            acc[1][2] = fmaf(a1, b2, acc[1][2]); acc[1][3] = fmaf(a1, b3, acc[1][3]);
            acc[2][0] = fmaf(a2, b0, acc[2][0]); acc[2][1] = fmaf(a2, b1, acc[2][1]);
            acc[2][2] = fmaf(a2, b2, acc[2][2]); acc[2][3] = fmaf(a2, b3, acc[2][3]);
            acc[3][0] = fmaf(a3, b0, acc[3][0]); acc[3][1] = fmaf(a3, b1, acc[3][1]);
            acc[3][2] = fmaf(a3, b2, acc[3][2]); acc[3][3] = fmaf(a3, b3, acc[3][3]);
        }
        __syncthreads();
    }
    // write xl + stage output tile into xs
    #pragma unroll
    for (int i = 0; i < 4; ++i) {
        int node = nbase + 4 * ty + i;
        xs[4 * ty + i][4 * tx + 0] = acc[i][0];
        xs[4 * ty + i][4 * tx + 1] = acc[i][1];
        xs[4 * ty + i][4 * tx + 2] = acc[i][2];
        xs[4 * ty + i][4 * tx + 3] = acc[i][3];
        if (node < n)
            *reinterpret_cast<float4*>(xl + (size_t)node * 64 + 4 * tx) =
                make_float4(acc[i][0], acc[i][1], acc[i][2], acc[i][3]);
    }
    __syncthreads();
    // attention logits: 64*H tasks
    for (int t = tid; t < 64 * H; t += 256) {
        int nl = t / H, h = t - nl * H;
        int node = nbase + nl;
        if (node < n) {
            float s = 0.f, d = 0.f;
            #pragma unroll
            for (int c = 0; c < CH; ++c) {
                float v = xs[nl][h * CH + c];
                s = fmaf(v, a_s[h * CH + c], s);
                d = fmaf(v, a_d[h * CH + c], d);
            }
            asrc[node * H + h] = s;
            adst[node * H + h] = d;
        }
    }
}

// ---------------- bucket sort ----------------
// hist_mat layout: [bucket][chunk]  (NBUCK x NSB)
__global__ __launch_bounds__(256)
void sort_hist(const int* __restrict__ dst, int E, int* __restrict__ hist_mat,
               int NBUCK, int NSB)
{
    __shared__ int h[MAXB];
    int tid = threadIdx.x, chunk = blockIdx.x;
    for (int b = tid; b < NBUCK; b += 256) h[b] = 0;
    __syncthreads();
    int base = chunk * CHUNK, end = min(base + CHUNK, E);
    for (int i = base + tid; i < end; i += 256)
        atomicAdd(&h[dst[i] >> BSH], 1);
    __syncthreads();
    for (int b = tid; b < NBUCK; b += 256)
        hist_mat[b * NSB + chunk] = h[b];
}

#define SCAN_SZ 2048   // 256 threads x 8
__global__ __launch_bounds__(256)
void scan1_kernel(const int* __restrict__ in, int* __restrict__ part,
                  int* __restrict__ sums, int m)
{
    __shared__ int lds[256];
    int base = blockIdx.x * SCAN_SZ;
    int t = threadIdx.x;
    int v[8]; int s = 0;
    #pragma unroll
    for (int j = 0; j < 8; ++j) {
        int idx = base + t * 8 + j;
        v[j] = (idx < m) ? in[idx] : 0;
        s += v[j];
    }
    lds[t] = s;
    __syncthreads();
    for (int off = 1; off < 256; off <<= 1) {
        int a = (t >= off) ? lds[t - off] : 0;
        __syncthreads();
        lds[t] += a;
        __syncthreads();
    }
    int run = lds[t] - s;
    if (t == 255) sums[blockIdx.x] = lds[t];
    #pragma unroll
    for (int j = 0; j < 8; ++j) {
        int idx = base + t * 8 + j;
        if (idx < m) part[idx] = run;
        run += v[j];
    }
}

__global__ void scan2_kernel(int* sums, int nb)
{
    if (threadIdx.x == 0 && blockIdx.x == 0) {
        int r = 0;
        for (int i = 0; i < nb; ++i) { int v = sums[i]; sums[i] = r; r += v; }
    }
}

__global__ __launch_bounds__(256)
void scan3_kernel(const int* __restrict__ part, const int* __restrict__ sums,
                  int* __restrict__ outp, int* __restrict__ bstart,
                  int m, int NSB, int NBUCK, int E)
{
    int i = blockIdx.x * 256 + threadIdx.x;
    if (i < m) {
        int v = part[i] + sums[i / SCAN_SZ];
        outp[i] = v;
        if (i % NSB == 0) bstart[i / NSB] = v;
    }
    if (i == 0) bstart[NBUCK] = E;
}

// placement: slot = scanned[bucket][chunk] + local rank (LDS cursor)
__global__ __launch_bounds__(256)
void sort_place(const int* __restrict__ src, const int* __restrict__ dst, int E,
                const int* __restrict__ scanned, int NBUCK, int NSB,
                unsigned* __restrict__ ssrc)
{
    __shared__ int cur[MAXB];
    int tid = threadIdx.x, chunk = blockIdx.x;
    for (int b = tid; b < NBUCK; b += 256) cur[b] = scanned[b * NSB + chunk];
    __syncthreads();
    int base = chunk * CHUNK, end = min(base + CHUNK, E);
    for (int i = base + tid; i < end; i += 256) {
        int d = dst[i];
        int b = d >> BSH;
        int slot = atomicAdd(&cur[b], 1);
        ssrc[slot] = ((unsigned)src[i] << BSH) | (unsigned)(d & 63);
    }
}

// ---------------- bucket aggregation, fully fused ----------------
// one block per bucket (64 nodes); LDS acc[64][64]; self-loop+norm+bias+act
// MODE 1: out = elu(v + b[64])    MODE 2: head-mean -> out[n,16] + b[16]
template<int H, int CH, int MODE>
__global__ __launch_bounds__(256)
void aggregate(const unsigned* __restrict__ ssrc, const int* __restrict__ bstart,
               const float* __restrict__ asrc, const float* __restrict__ adst,
               const float* __restrict__ xl, const float* __restrict__ bias,
               float* __restrict__ outp, int n)
{
    __shared__ float acc[64 * 64];
    __shared__ float den[64 * H];
    __shared__ float adl[64 * H];
    int tid = threadIdx.x;
    int lane = tid & 63;
    int w = tid >> 6;
    int bk = blockIdx.x;
    int nbase = bk << BSH;
    int h = lane / CH;

    for (int i = tid; i < 64 * 64; i += 256) acc[i] = 0.f;
    for (int i = tid; i < 64 * H; i += 256) {
        den[i] = 0.f;
        int node = nbase + i / H;
        adl[i] = (node < n) ? adst[node * H + (i % H)] : 0.f;
    }
    __syncthreads();

    int beg = bstart[bk], end = bstart[bk + 1];
    int i = beg + w;
    for (; i + 4 < end; i += 8) {
        unsigned e0 = ssrc[i], e1 = ssrc[i + 4];
        int s0 = e0 >> BSH, d0 = e0 & 63;
        int s1 = e1 >> BSH, d1 = e1 & 63;
        float l0 = asrc[s0 * H + h] + adl[d0 * H + h];
        float l1 = asrc[s1 * H + h] + adl[d1 * H + h];
        float x0 = xl[(size_t)s0 * 64 + lane];
        float x1 = xl[(size_t)s1 * 64 + lane];
        l0 = (l0 >= 0.f) ? l0 : LEAK * l0;
        l1 = (l1 >= 0.f) ? l1 : LEAK * l1;
        float p0 = __expf(l0), p1 = __expf(l1);
        atomicAdd(&acc[d0 * 64 + lane], p0 * x0);
        atomicAdd(&acc[d1 * 64 + lane], p1 * x1);
        if ((lane & (CH - 1)) == 0) {
            atomicAdd(&den[d0 * H + h], p0);
            atomicAdd(&den[d1 * H + h], p1);
        }
    }
    if (i < end) {
        unsigned e0 = ssrc[i];
        int s0 = e0 >> BSH, d0 = e0 & 63;
        float l0 = asrc[s0 * H + h] + adl[d0 * H + h];
        float x0 = xl[(size_t)s0 * 64 + lane];
        l0 = (l0 >= 0.f) ? l0 : LEAK * l0;
        float p0 = __expf(l0);
        atomicAdd(&acc[d0 * 64 + lane], p0 * x0);
        if ((lane & (CH - 1)) == 0) atomicAdd(&den[d0 * H + h], p0);
    }
    __syncthreads();

    // finalize: each wave handles 16 nodes; self-loop added directly
    for (int q = 0; q < 16; ++q) {
        int nl = w * 16 + q;
        int node = nbase + nl;
        if (node >= n) continue;
        float al = asrc[node * H + h] + adl[nl * H + h];
        al = (al >= 0.f) ? al : LEAK * al;
        float ps = __expf(al);
        float xv = xl[(size_t)node * 64 + lane];
        float num = acc[nl * 64 + lane] + ps * xv;
        float dn = den[nl * H + h] + ps;
        float v = num / fmaxf(dn, EPSV);
        if (MODE == 1) {
            v += bias[lane];
            outp[(size_t)node * 64 + lane] = (v > 0.f) ? v : expm1f(v);
        } else {
            v += __shfl_xor(v, 16);
            v += __shfl_xor(v, 32);
            if (lane < 16) outp[(size_t)node * 16 + lane] = 0.25f * v + bias[lane];
        }
    }
}

// ---------------- host ----------------
extern "C" void kernel_launch(void* const* d_in, const int* in_sizes, int n_in,
                              void* d_out, int out_size, void* d_ws, size_t ws_size,
                              hipStream_t stream)
{
    const float* x      = (const float*)d_in[0];
    const int*   ei     = (const int*)d_in[1];
    const float* W1     = (const float*)d_in[2];
    const float* a_src1 = (const float*)d_in[3];
    const float* a_dst1 = (const float*)d_in[4];
    const float* b1     = (const float*)d_in[5];
    const float* W2     = (const float*)d_in[6];
    const float* a_src2 = (const float*)d_in[7];
    const float* a_dst2 = (const float*)d_in[8];
    const float* b2     = (const float*)d_in[9];
    float* out = (float*)d_out;

    const int n = in_sizes[0] / 256;     // 50000
    const int E = in_sizes[1] / 2;       // 1600000
    const int* src = ei;
    const int* dst = ei + E;

    const int NSB   = (E + CHUNK - 1) / CHUNK;        // 98
    const int NBUCK = (n + 63) >> BSH;                // 782
    const int m     = NBUCK * NSB;                    // 76636
    const int nb    = (m + SCAN_SZ - 1) / SCAN_SZ;    // 38

    // workspace (floats/ints)
    size_t N64 = (size_t)n * 64;
    size_t N8  = (size_t)n * 8;
    float* xl     = (float*)d_ws;                 // N*64
    float* hbuf   = xl + N64;                     // N*64
    float* asrc   = hbuf + N64;                   // N*8
    float* adst   = asrc + N8;                    // N*8
    int*   histm  = (int*)(adst + N8);            // m
    int*   part   = histm + m;                    // m
    int*   scand  = part + m;                     // m
    int*   sums   = scand + m;                    // 64
    int*   bstart = sums + 64;                    // NBUCK+1
    unsigned* ssrc = (unsigned*)(bstart + NBUCK + 1);  // E
    (void)ws_size; (void)n_in; (void)out_size;

    // ----- bucket sort (graph shared by both layers) -----
    sort_hist<<<NSB, 256, 0, stream>>>(dst, E, histm, NBUCK, NSB);
    scan1_kernel<<<nb, 256, 0, stream>>>(histm, part, sums, m);
    scan2_kernel<<<1, 64, 0, stream>>>(sums, nb);
    scan3_kernel<<<(m + 255) / 256, 256, 0, stream>>>(part, sums, scand, bstart,
                                                      m, NSB, NBUCK, E);
    sort_place<<<NSB, 256, 0, stream>>>(src, dst, E, scand, NBUCK, NSB, ssrc);

    // ----- Layer 1: 256 -> 8x8, concat, +b1, ELU -----
    node_transform<256, 8, 8><<<(n + 63) / 64, 256, 0, stream>>>(
        x, W1, a_src1, a_dst1, xl, asrc, adst, n);
    aggregate<8, 8, 1><<<NBUCK, 256, 0, stream>>>(ssrc, bstart, asrc, adst,
                                                  xl, b1, hbuf, n);

    // ----- Layer 2: 64 -> 4x16, mean heads, +b2 -----
    node_transform<64, 4, 16><<<(n + 63) / 64, 256, 0, stream>>>(
        hbuf, W2, a_src2, a_dst2, xl, asrc, adst, n);
    aggregate<4, 16, 2><<<NBUCK, 256, 0, stream>>>(ssrc, bstart, asrc, adst,
                                                   xl, b2, out, n);
}

// Round 4
// 247.817 us; speedup vs baseline: 6.6278x; 6.6278x over previous
//
#include <hip/hip_runtime.h>
#include <math.h>

// 2-layer GAT (PyG GATConv), N=50000, E=1.6M, IN=256.
// Round 4:
//  - deterministic bucket sort by dst (kept from round 3, measured fast)
//  - NEW: within-bucket counting sort -> exact per-node CSR, 2-byte src ids
//  - NEW: aggregation = one wave per node, 4x16-lane edge groups, float4
//    row gathers, register accumulation, fused softmax/bias/activation
//  - tiled-GEMM node_transform (kept from round 3, measured fast)

#define LEAK 0.2f
#define EPSV 1e-16f
#define CHUNK 16384          // edges per sort block
#define BSH 6                // bucket shift: 64 nodes per bucket
#define MAXB 1024            // >= NBUCK (782)

// ---------------- tiled GEMM + attention epilogue ----------------
template<int K, int H, int CH>
__global__ __launch_bounds__(256)
void node_transform(const float* __restrict__ x, const float* __restrict__ W,
                    const float* __restrict__ a_s, const float* __restrict__ a_d,
                    float* __restrict__ xl, float* __restrict__ asrc,
                    float* __restrict__ adst, int n)
{
    __shared__ float xs[64][68];
    __shared__ float ws[64][64];
    int tid = threadIdx.x;
    int tx = tid & 15;
    int ty = tid >> 4;
    int nbase = blockIdx.x * 64;

    float acc[4][4] = {};
    for (int k0 = 0; k0 < K; k0 += 64) {
        #pragma unroll
        for (int r = ty; r < 64; r += 16) {
            int node = nbase + r;
            float4 v = make_float4(0.f, 0.f, 0.f, 0.f);
            if (node < n)
                v = *reinterpret_cast<const float4*>(x + (size_t)node * K + k0 + 4 * tx);
            xs[r][4 * tx + 0] = v.x; xs[r][4 * tx + 1] = v.y;
            xs[r][4 * tx + 2] = v.z; xs[r][4 * tx + 3] = v.w;
        }
        #pragma unroll
        for (int r = ty; r < 64; r += 16) {
            float4 w = *reinterpret_cast<const float4*>(W + (size_t)(k0 + r) * 64 + 4 * tx);
            ws[r][4 * tx + 0] = w.x; ws[r][4 * tx + 1] = w.y;
            ws[r][4 * tx + 2] = w.z; ws[r][4 * tx + 3] = w.w;
        }
        __syncthreads();
        #pragma unroll 8
        for (int k = 0; k < 64; ++k) {
            float a0 = xs[4 * ty + 0][k], a1 = xs[4 * ty + 1][k];
            float a2 = xs[4 * ty + 2][k], a3 = xs[4 * ty + 3][k];
            float b0 = ws[k][4 * tx + 0], b1 = ws[k][4 * tx + 1];
            float b2 = ws[k][4 * tx + 2], b3 = ws[k][4 * tx + 3];
            acc[0][0] = fmaf(a0, b0, acc[0][0]); acc[0][1] = fmaf(a0, b1, acc[0][1]);
            acc[0][2] = fmaf(a0, b2, acc[0][2]); acc[0][3] = fmaf(a0, b3, acc[0][3]);
            acc[1][0] = fmaf(a1, b0, acc[1][0]); acc[1][1] = fmaf(a1, b1, acc[1][1]);
            acc[1][2] = fmaf(a1, b2, acc[1][2]); acc[1][3] = fmaf(a1, b3, acc[1][3]);
            acc[2][0] = fmaf(a2, b0, acc[2][0]); acc[2][1] = fmaf(a2, b1, acc[2][1]);
            acc[2][2] = fmaf(a2, b2, acc[2][2]); acc[2][3] = fmaf(a2, b3, acc[2][3]);
            acc[3][0] = fmaf(a3, b0, acc[3][0]); acc[3][1] = fmaf(a3, b1, acc[3][1]);
            acc[3][2] = fmaf(a3, b2, acc[3][2]); acc[3][3] = fmaf(a3, b3, acc[3][3]);
        }
        __syncthreads();
    }
    #pragma unroll
    for (int i = 0; i < 4; ++i) {
        int node = nbase + 4 * ty + i;
        xs[4 * ty + i][4 * tx + 0] = acc[i][0];
        xs[4 * ty + i][4 * tx + 1] = acc[i][1];
        xs[4 * ty + i][4 * tx + 2] = acc[i][2];
        xs[4 * ty + i][4 * tx + 3] = acc[i][3];
        if (node < n)
            *reinterpret_cast<float4*>(xl + (size_t)node * 64 + 4 * tx) =
                make_float4(acc[i][0], acc[i][1], acc[i][2], acc[i][3]);
    }
    __syncthreads();
    for (int t = tid; t < 64 * H; t += 256) {
        int nl = t / H, h = t - nl * H;
        int node = nbase + nl;
        if (node < n) {
            float s = 0.f, d = 0.f;
            #pragma unroll
            for (int c = 0; c < CH; ++c) {
                float v = xs[nl][h * CH + c];
                s = fmaf(v, a_s[h * CH + c], s);
                d = fmaf(v, a_d[h * CH + c], d);
            }
            asrc[node * H + h] = s;
            adst[node * H + h] = d;
        }
    }
}

// ---------------- bucket sort (deterministic) ----------------
__global__ __launch_bounds__(256)
void sort_hist(const int* __restrict__ dst, int E, int* __restrict__ hist_mat,
               int NBUCK, int NSB)
{
    __shared__ int h[MAXB];
    int tid = threadIdx.x, chunk = blockIdx.x;
    for (int b = tid; b < NBUCK; b += 256) h[b] = 0;
    __syncthreads();
    int base = chunk * CHUNK, end = min(base + CHUNK, E);
    for (int i = base + tid; i < end; i += 256)
        atomicAdd(&h[dst[i] >> BSH], 1);
    __syncthreads();
    for (int b = tid; b < NBUCK; b += 256)
        hist_mat[b * NSB + chunk] = h[b];
}

#define SCAN_SZ 2048
__global__ __launch_bounds__(256)
void scan1_kernel(const int* __restrict__ in, int* __restrict__ part,
                  int* __restrict__ sums, int m)
{
    __shared__ int lds[256];
    int base = blockIdx.x * SCAN_SZ;
    int t = threadIdx.x;
    int v[8]; int s = 0;
    #pragma unroll
    for (int j = 0; j < 8; ++j) {
        int idx = base + t * 8 + j;
        v[j] = (idx < m) ? in[idx] : 0;
        s += v[j];
    }
    lds[t] = s;
    __syncthreads();
    for (int off = 1; off < 256; off <<= 1) {
        int a = (t >= off) ? lds[t - off] : 0;
        __syncthreads();
        lds[t] += a;
        __syncthreads();
    }
    int run = lds[t] - s;
    if (t == 255) sums[blockIdx.x] = lds[t];
    #pragma unroll
    for (int j = 0; j < 8; ++j) {
        int idx = base + t * 8 + j;
        if (idx < m) part[idx] = run;
        run += v[j];
    }
}

__global__ void scan2_kernel(int* sums, int nb)
{
    if (threadIdx.x == 0 && blockIdx.x == 0) {
        int r = 0;
        for (int i = 0; i < nb; ++i) { int v = sums[i]; sums[i] = r; r += v; }
    }
}

__global__ __launch_bounds__(256)
void scan3_kernel(const int* __restrict__ part, const int* __restrict__ sums,
                  int* __restrict__ outp, int* __restrict__ bstart,
                  int m, int NSB, int NBUCK, int E)
{
    int i = blockIdx.x * 256 + threadIdx.x;
    if (i < m) {
        int v = part[i] + sums[i / SCAN_SZ];
        outp[i] = v;
        if (i % NSB == 0) bstart[i / NSB] = v;
    }
    if (i == 0) bstart[NBUCK] = E;
}

__global__ __launch_bounds__(256)
void sort_place(const int* __restrict__ src, const int* __restrict__ dst, int E,
                const int* __restrict__ scanned, int NBUCK, int NSB,
                unsigned* __restrict__ ssrc)
{
    __shared__ int cur[MAXB];
    int tid = threadIdx.x, chunk = blockIdx.x;
    for (int b = tid; b < NBUCK; b += 256) cur[b] = scanned[b * NSB + chunk];
    __syncthreads();
    int base = chunk * CHUNK, end = min(base + CHUNK, E);
    for (int i = base + tid; i < end; i += 256) {
        int d = dst[i];
        int b = d >> BSH;
        int slot = atomicAdd(&cur[b], 1);
        ssrc[slot] = ((unsigned)src[i] << BSH) | (unsigned)(d & 63);
    }
}

// ---------------- within-bucket counting sort -> per-node CSR ----------------
__global__ __launch_bounds__(256)
void bucket_nodesort(const unsigned* __restrict__ ssrc, const int* __restrict__ bstart,
                     unsigned short* __restrict__ ssrc2, int* __restrict__ offs,
                     int n, int NBUCK, int E)
{
    __shared__ int cnt[64];
    __shared__ int base_[64];
    int bk = blockIdx.x, tid = threadIdx.x;
    int beg = bstart[bk], end = bstart[bk + 1];
    if (tid < 64) cnt[tid] = 0;
    __syncthreads();
    for (int i = beg + tid; i < end; i += 256)
        atomicAdd(&cnt[ssrc[i] & 63], 1);
    __syncthreads();
    if (tid == 0) {
        int r = 0;
        for (int j = 0; j < 64; ++j) { int c = cnt[j]; base_[j] = r; r += c; }
    }
    __syncthreads();
    if (tid < 64) {
        int node = (bk << BSH) + tid;
        if (node < n) offs[node] = beg + base_[tid];
        cnt[tid] = 0;    // reuse as cursor
    }
    __syncthreads();
    for (int i = beg + tid; i < end; i += 256) {
        unsigned e = ssrc[i];
        int dl = e & 63;
        int r = atomicAdd(&cnt[dl], 1);
        ssrc2[beg + base_[dl] + r] = (unsigned short)(e >> BSH);
    }
    if (bk == 0 && tid == 0) offs[n] = E;
}

// ---------------- per-node wave aggregation, 4x16-lane edge groups ----------
// lane = 16*g + subl; group g processes edges beg+g, beg+g+4, ...
// each lane accumulates float4 of channels 4*subl..4*subl+3 + per-head denom.
// MODE 1: out = elu(v + b[64])    MODE 2: head-mean -> out[n,16] + b[16]
template<int H, int CH, int MODE>
__global__ __launch_bounds__(256)
void aggregate_csr(const int* __restrict__ offs, const unsigned short* __restrict__ ssrc2,
                   const float* __restrict__ asrc, const float* __restrict__ adst,
                   const float* __restrict__ xl, const float* __restrict__ bias,
                   float* __restrict__ outp, int n)
{
    int wid = blockIdx.x * 4 + (threadIdx.x >> 6);
    if (wid >= n) return;
    int lane = threadIdx.x & 63;
    int g = lane >> 4;
    int subl = lane & 15;
    int h = (subl * 4) / CH;          // head owning my 4 channels
    int d = wid;

    float ad = adst[d * H + h];
    int beg = offs[d], end = offs[d + 1];

    float4 acc = make_float4(0.f, 0.f, 0.f, 0.f);
    float den = 0.f;
    #pragma unroll 2
    for (int i = beg + g; i < end; i += 4) {
        int s = ssrc2[i];
        float l = asrc[s * H + h] + ad;
        l = (l >= 0.f) ? l : LEAK * l;
        float p = __expf(l);
        float4 xv = *reinterpret_cast<const float4*>(xl + (size_t)s * 64 + 4 * subl);
        den += p;
        acc.x = fmaf(p, xv.x, acc.x);
        acc.y = fmaf(p, xv.y, acc.y);
        acc.z = fmaf(p, xv.z, acc.z);
        acc.w = fmaf(p, xv.w, acc.w);
    }
    // combine the 4 edge groups (lanes differing in bits 4,5)
    acc.x += __shfl_xor(acc.x, 16); acc.y += __shfl_xor(acc.y, 16);
    acc.z += __shfl_xor(acc.z, 16); acc.w += __shfl_xor(acc.w, 16);
    den   += __shfl_xor(den,   16);
    acc.x += __shfl_xor(acc.x, 32); acc.y += __shfl_xor(acc.y, 32);
    acc.z += __shfl_xor(acc.z, 32); acc.w += __shfl_xor(acc.w, 32);
    den   += __shfl_xor(den,   32);

    // self-loop (added once; all lanes hold identical reduced copies)
    {
        float l = asrc[d * H + h] + ad;
        l = (l >= 0.f) ? l : LEAK * l;
        float ps = __expf(l);
        float4 xv = *reinterpret_cast<const float4*>(xl + (size_t)d * 64 + 4 * subl);
        den += ps;
        acc.x = fmaf(ps, xv.x, acc.x);
        acc.y = fmaf(ps, xv.y, acc.y);
        acc.z = fmaf(ps, xv.z, acc.z);
        acc.w = fmaf(ps, xv.w, acc.w);
    }
    float inv = 1.f / fmaxf(den, EPSV);
    float4 v = make_float4(acc.x * inv, acc.y * inv, acc.z * inv, acc.w * inv);

    if (MODE == 1) {
        float4 b4 = reinterpret_cast<const float4*>(bias)[subl];
        v.x += b4.x; v.y += b4.y; v.z += b4.z; v.w += b4.w;
        v.x = (v.x > 0.f) ? v.x : expm1f(v.x);
        v.y = (v.y > 0.f) ? v.y : expm1f(v.y);
        v.z = (v.z > 0.f) ? v.z : expm1f(v.z);
        v.w = (v.w > 0.f) ? v.w : expm1f(v.w);
        if (g == 0)
            *reinterpret_cast<float4*>(outp + (size_t)d * 64 + 4 * subl) = v;
    } else {
        // mean over H=4 heads: head = subl>>2 -> sum over subl bits 2,3
        v.x += __shfl_xor(v.x, 4); v.y += __shfl_xor(v.y, 4);
        v.z += __shfl_xor(v.z, 4); v.w += __shfl_xor(v.w, 4);
        v.x += __shfl_xor(v.x, 8); v.y += __shfl_xor(v.y, 8);
        v.z += __shfl_xor(v.z, 8); v.w += __shfl_xor(v.w, 8);
        if (lane < 4) {
            float4 b4 = reinterpret_cast<const float4*>(bias)[subl];
            float4 o = make_float4(0.25f * v.x + b4.x, 0.25f * v.y + b4.y,
                                   0.25f * v.z + b4.z, 0.25f * v.w + b4.w);
            *reinterpret_cast<float4*>(outp + (size_t)d * 16 + 4 * subl) = o;
        }
    }
}

// ---------------- host ----------------
extern "C" void kernel_launch(void* const* d_in, const int* in_sizes, int n_in,
                              void* d_out, int out_size, void* d_ws, size_t ws_size,
                              hipStream_t stream)
{
    const float* x      = (const float*)d_in[0];
    const int*   ei     = (const int*)d_in[1];
    const float* W1     = (const float*)d_in[2];
    const float* a_src1 = (const float*)d_in[3];
    const float* a_dst1 = (const float*)d_in[4];
    const float* b1     = (const float*)d_in[5];
    const float* W2     = (const float*)d_in[6];
    const float* a_src2 = (const float*)d_in[7];
    const float* a_dst2 = (const float*)d_in[8];
    const float* b2     = (const float*)d_in[9];
    float* out = (float*)d_out;

    const int n = in_sizes[0] / 256;     // 50000
    const int E = in_sizes[1] / 2;       // 1600000
    const int* src = ei;
    const int* dst = ei + E;

    const int NSB   = (E + CHUNK - 1) / CHUNK;        // 98
    const int NBUCK = (n + 63) >> BSH;                // 782
    const int m     = NBUCK * NSB;                    // 76636
    const int nb    = (m + SCAN_SZ - 1) / SCAN_SZ;    // 38

    size_t N64 = (size_t)n * 64;
    size_t N8  = (size_t)n * 8;
    float* xl     = (float*)d_ws;                     // N*64
    float* hbuf   = xl + N64;                         // N*64
    float* asrc   = hbuf + N64;                       // N*8
    float* adst   = asrc + N8;                        // N*8
    int*   histm  = (int*)(adst + N8);                // m
    int*   part   = histm + m;                        // m
    int*   scand  = part + m;                         // m
    int*   sums   = scand + m;                        // 64
    int*   bstart = sums + 64;                        // NBUCK+1
    int*   offs   = bstart + NBUCK + 1;               // n+1
    unsigned* ssrc = (unsigned*)(offs + n + 1);       // E (4B)
    unsigned short* ssrc2 = (unsigned short*)(ssrc + E);  // E (2B)
    (void)ws_size; (void)n_in; (void)out_size;

    // ----- bucket sort + per-node CSR (graph shared by both layers) -----
    sort_hist<<<NSB, 256, 0, stream>>>(dst, E, histm, NBUCK, NSB);
    scan1_kernel<<<nb, 256, 0, stream>>>(histm, part, sums, m);
    scan2_kernel<<<1, 64, 0, stream>>>(sums, nb);
    scan3_kernel<<<(m + 255) / 256, 256, 0, stream>>>(part, sums, scand, bstart,
                                                      m, NSB, NBUCK, E);
    sort_place<<<NSB, 256, 0, stream>>>(src, dst, E, scand, NBUCK, NSB, ssrc);
    bucket_nodesort<<<NBUCK, 256, 0, stream>>>(ssrc, bstart, ssrc2, offs, n, NBUCK, E);

    // ----- Layer 1: 256 -> 8x8, concat, +b1, ELU -----
    node_transform<256, 8, 8><<<(n + 63) / 64, 256, 0, stream>>>(
        x, W1, a_src1, a_dst1, xl, asrc, adst, n);
    aggregate_csr<8, 8, 1><<<(n + 3) / 4, 256, 0, stream>>>(offs, ssrc2, asrc, adst,
                                                            xl, b1, hbuf, n);

    // ----- Layer 2: 64 -> 4x16, mean heads, +b2 -----
    node_transform<64, 4, 16><<<(n + 63) / 64, 256, 0, stream>>>(
        hbuf, W2, a_src2, a_dst2, xl, asrc, adst, n);
    aggregate_csr<4, 16, 2><<<(n + 3) / 4, 256, 0, stream>>>(offs, ssrc2, asrc, adst,
                                                             xl, b2, out, n);
}